// Round 1
// baseline (966.094 us; speedup 1.0000x reference)
//
#include <hip/hip_runtime.h>
#include <hip/hip_bf16.h>
#include <math.h>

#define N_NODES 50000
#define N_EDGES 800000
#define E_TOT   (N_EDGES + N_NODES)   // edges + self-loops
#define NEG_SLOPE 0.2f

__device__ __forceinline__ float lrelu(float x) { return x >= 0.f ? x : NEG_SLOPE * x; }

__device__ __forceinline__ void atomicMaxFloat(float* addr, float val) {
    // works for any mix of signs; addr must be initialized to -inf
    if (val >= 0.f) atomicMax((int*)addr, __float_as_int(val));
    else            atomicMin((unsigned int*)addr, __float_as_uint(val));
}

// ---- init: emax = -inf, denom = 0 (both layers) ----
__global__ void init_misc(float* emax1, float* denom1, float* emax2, float* denom2) {
    int i = blockIdx.x * blockDim.x + threadIdx.x;
    if (i < N_NODES * 4) { emax1[i] = -INFINITY; denom1[i] = 0.f; }
    if (i < N_NODES)     { emax2[i] = -INFINITY; denom2[i] = 0.f; }
}

// ---- layer 1 GEMM: h1 = x @ W1, fused a_s1/a_d1 ----
// block = 128 threads (one node per block), thread j computes h1[n][j]
__global__ void gemm1(const float* __restrict__ x, const float* __restrict__ W1,
                      const float* __restrict__ att_s, const float* __restrict__ att_d,
                      float* __restrict__ h1, float* __restrict__ as1, float* __restrict__ ad1) {
    int n = blockIdx.x;
    int j = threadIdx.x;            // 0..127
    __shared__ float xs[64];
    if (j < 64) xs[j] = x[n * 64 + j];
    __syncthreads();
    float acc = 0.f;
#pragma unroll
    for (int k = 0; k < 64; ++k) acc += xs[k] * W1[k * 128 + j];
    h1[n * 128 + j] = acc;
    int h = j >> 5, l = j & 31;
    float ps = acc * att_s[h * 32 + l];
    float pd = acc * att_d[h * 32 + l];
    // reduce over the 32 lanes of this head (xor masks < 32 stay in-group on wave64)
    for (int m = 16; m >= 1; m >>= 1) {
        ps += __shfl_xor(ps, m, 64);
        pd += __shfl_xor(pd, m, 64);
    }
    if (l == 0) { as1[n * 4 + h] = ps; ad1[n * 4 + h] = pd; }
}

__device__ __forceinline__ void edge_sd(const int* __restrict__ ei, int e, int& s, int& d) {
    if (e < N_EDGES) { s = ei[e]; d = ei[N_EDGES + e]; }
    else             { s = d = e - N_EDGES; }
}

// ---- layer 1 edge pass A: segment max ----
__global__ void edge_max1(const int* __restrict__ ei, const float* __restrict__ as1,
                          const float* __restrict__ ad1, float* __restrict__ emax1) {
    int e = blockIdx.x * blockDim.x + threadIdx.x;
    if (e >= E_TOT) return;
    int s, d; edge_sd(ei, e, s, d);
    float4 a = *(const float4*)(as1 + s * 4);
    float4 b = *(const float4*)(ad1 + d * 4);
    atomicMaxFloat(&emax1[d * 4 + 0], lrelu(a.x + b.x));
    atomicMaxFloat(&emax1[d * 4 + 1], lrelu(a.y + b.y));
    atomicMaxFloat(&emax1[d * 4 + 2], lrelu(a.z + b.z));
    atomicMaxFloat(&emax1[d * 4 + 3], lrelu(a.w + b.w));
}

// ---- layer 1 edge pass B: denom = segment sum of exp(e - emax) ----
__global__ void edge_sum1(const int* __restrict__ ei, const float* __restrict__ as1,
                          const float* __restrict__ ad1, const float* __restrict__ emax1,
                          float* __restrict__ denom1) {
    int e = blockIdx.x * blockDim.x + threadIdx.x;
    if (e >= E_TOT) return;
    int s, d; edge_sd(ei, e, s, d);
    float4 a = *(const float4*)(as1 + s * 4);
    float4 b = *(const float4*)(ad1 + d * 4);
    float4 m = *(const float4*)(emax1 + d * 4);
    atomicAdd(&denom1[d * 4 + 0], expf(lrelu(a.x + b.x) - m.x));
    atomicAdd(&denom1[d * 4 + 1], expf(lrelu(a.y + b.y) - m.y));
    atomicAdd(&denom1[d * 4 + 2], expf(lrelu(a.z + b.z) - m.z));
    atomicAdd(&denom1[d * 4 + 3], expf(lrelu(a.w + b.w) - m.w));
}

// ---- layer 1 edge pass C: agg1[dst] += alpha * h1[src]  (128 dims/edge) ----
__global__ void edge_agg1(const int* __restrict__ ei, const float* __restrict__ as1,
                          const float* __restrict__ ad1, const float* __restrict__ emax1,
                          const float* __restrict__ denom1, const float* __restrict__ h1,
                          float* __restrict__ agg1) {
    int t = blockIdx.x * blockDim.x + threadIdx.x;   // < E_TOT*128 (108.8M, fits int)
    int e = t >> 7;
    if (e >= E_TOT) return;
    int j = t & 127;
    int h = j >> 5;
    int s, d; edge_sd(ei, e, s, d);
    float ev = lrelu(as1[s * 4 + h] + ad1[d * 4 + h]);
    float alpha = expf(ev - emax1[d * 4 + h]) / denom1[d * 4 + h];
    atomicAdd(&agg1[d * 128 + j], h1[s * 128 + j] * alpha);
}

// ---- bias + ELU in place on agg1 ----
__global__ void bias_elu(float* __restrict__ agg1, const float* __restrict__ b1) {
    int i = blockIdx.x * blockDim.x + threadIdx.x;
    if (i >= N_NODES * 128) return;
    float v = agg1[i] + b1[i & 127];
    agg1[i] = v > 0.f ? v : expm1f(v);
}

// ---- layer 2 GEMM: h2 = h @ W2, fused a_s2/a_d2; block=128 -> 4 nodes ----
__global__ void gemm2(const float* __restrict__ hsrc, const float* __restrict__ W2,
                      const float* __restrict__ att_s2, const float* __restrict__ att_d2,
                      float* __restrict__ h2, float* __restrict__ as2, float* __restrict__ ad2) {
    int nb = blockIdx.x * 4;
    int j = threadIdx.x;            // 0..127
    int nl = j >> 5, l = j & 31;
    __shared__ float hs[4][128];
    for (int i = j; i < 512; i += 128) hs[i >> 7][i & 127] = hsrc[nb * 128 + i];
    __syncthreads();
    int n = nb + nl;
    float acc = 0.f;
#pragma unroll
    for (int k = 0; k < 128; ++k) acc += hs[nl][k] * W2[k * 32 + l];
    h2[n * 32 + l] = acc;
    float ps = acc * att_s2[l];
    float pd = acc * att_d2[l];
    for (int m = 16; m >= 1; m >>= 1) {
        ps += __shfl_xor(ps, m, 64);
        pd += __shfl_xor(pd, m, 64);
    }
    if (l == 0) { as2[n] = ps; ad2[n] = pd; }
}

// ---- layer 2 edge passes (1 head) ----
__global__ void edge_max2(const int* __restrict__ ei, const float* __restrict__ as2,
                          const float* __restrict__ ad2, float* __restrict__ emax2) {
    int e = blockIdx.x * blockDim.x + threadIdx.x;
    if (e >= E_TOT) return;
    int s, d; edge_sd(ei, e, s, d);
    atomicMaxFloat(&emax2[d], lrelu(as2[s] + ad2[d]));
}

__global__ void edge_sum2(const int* __restrict__ ei, const float* __restrict__ as2,
                          const float* __restrict__ ad2, const float* __restrict__ emax2,
                          float* __restrict__ denom2) {
    int e = blockIdx.x * blockDim.x + threadIdx.x;
    if (e >= E_TOT) return;
    int s, d; edge_sd(ei, e, s, d);
    atomicAdd(&denom2[d], expf(lrelu(as2[s] + ad2[d]) - emax2[d]));
}

__global__ void edge_agg2(const int* __restrict__ ei, const float* __restrict__ as2,
                          const float* __restrict__ ad2, const float* __restrict__ emax2,
                          const float* __restrict__ denom2, const float* __restrict__ h2,
                          float* __restrict__ out) {
    int t = blockIdx.x * blockDim.x + threadIdx.x;   // < E_TOT*32 (27.2M)
    int e = t >> 5;
    if (e >= E_TOT) return;
    int j = t & 31;
    int s, d; edge_sd(ei, e, s, d);
    float ev = lrelu(as2[s] + ad2[d]);
    float alpha = expf(ev - emax2[d]) / denom2[d];
    atomicAdd(&out[d * 32 + j], h2[s * 32 + j] * alpha);
}

__global__ void bias2_add(float* __restrict__ out, const float* __restrict__ b2) {
    int i = blockIdx.x * blockDim.x + threadIdx.x;
    if (i >= N_NODES * 32) return;
    out[i] += b2[i & 31];
}

extern "C" void kernel_launch(void* const* d_in, const int* in_sizes, int n_in,
                              void* d_out, int out_size, void* d_ws, size_t ws_size,
                              hipStream_t stream) {
    const float* x        = (const float*)d_in[0];
    const int*   ei       = (const int*)d_in[1];
    const float* W1       = (const float*)d_in[2];
    const float* att_src1 = (const float*)d_in[3];
    const float* att_dst1 = (const float*)d_in[4];
    const float* b1       = (const float*)d_in[5];
    const float* W2       = (const float*)d_in[6];
    const float* att_src2 = (const float*)d_in[7];
    const float* att_dst2 = (const float*)d_in[8];
    const float* b2       = (const float*)d_in[9];
    float* out = (float*)d_out;

    // workspace carve-up (floats): total ~15.4M floats ~= 62 MB
    float* p = (float*)d_ws;
    float* h1    = p; p += N_NODES * 128;
    float* agg1  = p; p += N_NODES * 128;
    float* h2    = p; p += N_NODES * 32;
    float* as1   = p; p += N_NODES * 4;
    float* ad1   = p; p += N_NODES * 4;
    float* emax1 = p; p += N_NODES * 4;
    float* denom1= p; p += N_NODES * 4;
    float* as2   = p; p += N_NODES;
    float* ad2   = p; p += N_NODES;
    float* emax2 = p; p += N_NODES;
    float* denom2= p; p += N_NODES;

    hipMemsetAsync(agg1, 0, (size_t)N_NODES * 128 * sizeof(float), stream);
    hipMemsetAsync(out,  0, (size_t)N_NODES * 32 * sizeof(float), stream);
    init_misc<<<(N_NODES * 4 + 255) / 256, 256, 0, stream>>>(emax1, denom1, emax2, denom2);

    // ---- layer 1 ----
    gemm1<<<N_NODES, 128, 0, stream>>>(x, W1, att_src1, att_dst1, h1, as1, ad1);
    int egrid = (E_TOT + 255) / 256;
    edge_max1<<<egrid, 256, 0, stream>>>(ei, as1, ad1, emax1);
    edge_sum1<<<egrid, 256, 0, stream>>>(ei, as1, ad1, emax1, denom1);
    edge_agg1<<<(E_TOT * 128) / 256, 256, 0, stream>>>(ei, as1, ad1, emax1, denom1, h1, agg1);
    bias_elu<<<(N_NODES * 128 + 255) / 256, 256, 0, stream>>>(agg1, b1);

    // ---- layer 2 ----
    gemm2<<<N_NODES / 4, 128, 0, stream>>>(agg1, W2, att_src2, att_dst2, h2, as2, ad2);
    edge_max2<<<egrid, 256, 0, stream>>>(ei, as2, ad2, emax2);
    edge_sum2<<<egrid, 256, 0, stream>>>(ei, as2, ad2, emax2, denom2);
    edge_agg2<<<(E_TOT * 32 + 255) / 256, 256, 0, stream>>>(ei, as2, ad2, emax2, denom2, h2, out);
    bias2_add<<<(N_NODES * 32 + 255) / 256, 256, 0, stream>>>(out, b2);
}

// Round 2
// 387.909 us; speedup vs baseline: 2.4905x; 2.4905x over previous
//
#include <hip/hip_runtime.h>
#include <hip/hip_bf16.h>
#include <math.h>

#define N_NODES 50000
#define N_EDGES 800000
#define E_TOT   (N_EDGES + N_NODES)   // edges + self-loops
#define NEG_SLOPE 0.2f
#define SCAN_BLK 512

__device__ __forceinline__ float lrelu(float x) { return x >= 0.f ? x : NEG_SLOPE * x; }

__device__ __forceinline__ void edge_sd(const int* __restrict__ ei, int e, int& s, int& d) {
    if (e < N_EDGES) { s = ei[e]; d = ei[N_EDGES + e]; }
    else             { s = d = e - N_EDGES; }
}

// ======================= CSR build (by dst) =======================
__global__ void count_edges(const int* __restrict__ ei, int* __restrict__ cnt) {
    int e = blockIdx.x * blockDim.x + threadIdx.x;
    if (e >= E_TOT) return;
    int d = (e < N_EDGES) ? ei[N_EDGES + e] : e - N_EDGES;
    atomicAdd(&cnt[d], 1);
}

__global__ void scan_block(const int* __restrict__ cnt, int* __restrict__ offs,
                           int* __restrict__ bsums) {
    __shared__ int s[SCAN_BLK];
    int b = blockIdx.x, t = threadIdx.x;
    int i = b * SCAN_BLK + t;
    int v = (i < N_NODES) ? cnt[i] : 0;
    s[t] = v;
    __syncthreads();
    for (int off = 1; off < SCAN_BLK; off <<= 1) {
        int x = (t >= off) ? s[t - off] : 0;
        __syncthreads();
        s[t] += x;
        __syncthreads();
    }
    if (i < N_NODES) offs[i] = s[t] - v;   // exclusive
    if (t == SCAN_BLK - 1) bsums[b] = s[t];
}

__global__ void scan_bsums(int* __restrict__ bsums, int nb) {
    if (threadIdx.x == 0 && blockIdx.x == 0) {
        int acc = 0;
        for (int i = 0; i < nb; ++i) { int v = bsums[i]; bsums[i] = acc; acc += v; }
    }
}

__global__ void scan_add(int* __restrict__ offs, const int* __restrict__ bsums) {
    int b = blockIdx.x, t = threadIdx.x;
    int i = b * SCAN_BLK + t;
    if (i < N_NODES) offs[i] += bsums[b];
    if (b == 0 && t == 0) offs[N_NODES] = E_TOT;
}

__global__ void scatter_edges(const int* __restrict__ ei, const int* __restrict__ offs,
                              int* __restrict__ fill, int* __restrict__ csr) {
    int e = blockIdx.x * blockDim.x + threadIdx.x;
    if (e >= E_TOT) return;
    int s, d; edge_sd(ei, e, s, d);
    int pos = offs[d] + atomicAdd(&fill[d], 1);
    csr[pos] = s;
}

// ======================= layer 1 GEMM =======================
// block = 128 threads (one node per block), thread j computes h1[n][j]
__global__ void gemm1(const float* __restrict__ x, const float* __restrict__ W1,
                      const float* __restrict__ att_s, const float* __restrict__ att_d,
                      float* __restrict__ h1, float* __restrict__ as1, float* __restrict__ ad1) {
    int n = blockIdx.x;
    int j = threadIdx.x;            // 0..127
    __shared__ float xs[64];
    if (j < 64) xs[j] = x[n * 64 + j];
    __syncthreads();
    float acc = 0.f;
#pragma unroll
    for (int k = 0; k < 64; ++k) acc += xs[k] * W1[k * 128 + j];
    h1[n * 128 + j] = acc;
    int h = j >> 5, l = j & 31;
    float ps = acc * att_s[h * 32 + l];
    float pd = acc * att_d[h * 32 + l];
    for (int m = 16; m >= 1; m >>= 1) {
        ps += __shfl_xor(ps, m, 64);
        pd += __shfl_xor(pd, m, 64);
    }
    if (l == 0) { as1[n * 4 + h] = ps; ad1[n * 4 + h] = pd; }
}

// ======================= layer 1 fused node aggregation =======================
// one block (128 threads) per dst node: segment max, denom, weighted agg,
// bias + ELU — no atomics.
__global__ void node_agg1(const int* __restrict__ offs, const int* __restrict__ csr,
                          const float* __restrict__ as1, const float* __restrict__ ad1,
                          const float* __restrict__ h1, const float* __restrict__ b1,
                          float* __restrict__ hact) {
    int n = blockIdx.x;
    int j = threadIdx.x;            // 0..127
    int h = j >> 5;
    int beg = offs[n], end = offs[n + 1];

    float ad0 = ad1[n * 4 + 0], ad1v = ad1[n * 4 + 1];
    float ad2v = ad1[n * 4 + 2], ad3v = ad1[n * 4 + 3];

    __shared__ float4 red[128];

    // ---- phase 1: per-head max over incoming edges ----
    float4 mx = make_float4(-INFINITY, -INFINITY, -INFINITY, -INFINITY);
    for (int p = beg + j; p < end; p += 128) {
        int s = csr[p];
        float4 a = *(const float4*)(as1 + s * 4);
        mx.x = fmaxf(mx.x, lrelu(a.x + ad0));
        mx.y = fmaxf(mx.y, lrelu(a.y + ad1v));
        mx.z = fmaxf(mx.z, lrelu(a.z + ad2v));
        mx.w = fmaxf(mx.w, lrelu(a.w + ad3v));
    }
    red[j] = mx;
    __syncthreads();
    for (int st = 64; st >= 1; st >>= 1) {
        if (j < st) {
            float4 o = red[j + st];
            float4 m = red[j];
            red[j] = make_float4(fmaxf(m.x, o.x), fmaxf(m.y, o.y),
                                 fmaxf(m.z, o.z), fmaxf(m.w, o.w));
        }
        __syncthreads();
    }
    float4 MX = red[0];
    __syncthreads();

    // ---- phase 2: per-head denom ----
    float4 dn = make_float4(0.f, 0.f, 0.f, 0.f);
    for (int p = beg + j; p < end; p += 128) {
        int s = csr[p];
        float4 a = *(const float4*)(as1 + s * 4);
        dn.x += expf(lrelu(a.x + ad0) - MX.x);
        dn.y += expf(lrelu(a.y + ad1v) - MX.y);
        dn.z += expf(lrelu(a.z + ad2v) - MX.z);
        dn.w += expf(lrelu(a.w + ad3v) - MX.w);
    }
    red[j] = dn;
    __syncthreads();
    for (int st = 64; st >= 1; st >>= 1) {
        if (j < st) {
            float4 o = red[j + st];
            float4 m = red[j];
            red[j] = make_float4(m.x + o.x, m.y + o.y, m.z + o.z, m.w + o.w);
        }
        __syncthreads();
    }
    float4 DN = red[0];

    float adh = (h == 0) ? ad0 : (h == 1) ? ad1v : (h == 2) ? ad2v : ad3v;
    float mxh = (h == 0) ? MX.x : (h == 1) ? MX.y : (h == 2) ? MX.z : MX.w;
    float rdh = 1.f / ((h == 0) ? DN.x : (h == 1) ? DN.y : (h == 2) ? DN.z : DN.w);

    // ---- phase 3: weighted aggregation over edges, dim j ----
    float acc = 0.f;
    for (int p = beg; p < end; ++p) {
        int s = csr[p];
        float av = as1[s * 4 + h];                       // broadcast per 32-lane group
        float alpha = expf(lrelu(av + adh) - mxh) * rdh;
        acc += alpha * h1[s * 128 + j];                  // coalesced 512B gather
    }
    float v = acc + b1[j];
    hact[n * 128 + j] = v > 0.f ? v : expm1f(v);
}

// ======================= layer 2 GEMM =======================
__global__ void gemm2(const float* __restrict__ hsrc, const float* __restrict__ W2,
                      const float* __restrict__ att_s2, const float* __restrict__ att_d2,
                      float* __restrict__ h2, float* __restrict__ as2, float* __restrict__ ad2) {
    int nb = blockIdx.x * 4;
    int j = threadIdx.x;            // 0..127
    int nl = j >> 5, l = j & 31;
    __shared__ float hs[4][128];
    for (int i = j; i < 512; i += 128) hs[i >> 7][i & 127] = hsrc[nb * 128 + i];
    __syncthreads();
    int n = nb + nl;
    float acc = 0.f;
#pragma unroll
    for (int k = 0; k < 128; ++k) acc += hs[nl][k] * W2[k * 32 + l];
    h2[n * 32 + l] = acc;
    float ps = acc * att_s2[l];
    float pd = acc * att_d2[l];
    for (int m = 16; m >= 1; m >>= 1) {
        ps += __shfl_xor(ps, m, 64);
        pd += __shfl_xor(pd, m, 64);
    }
    if (l == 0) { as2[n] = ps; ad2[n] = pd; }
}

// ======================= layer 2 fused node aggregation =======================
// block = 128 threads = 4 nodes x 32 lanes; 1 head, 32 dims; bias fused.
__global__ void node_agg2(const int* __restrict__ offs, const int* __restrict__ csr,
                          const float* __restrict__ as2, const float* __restrict__ ad2,
                          const float* __restrict__ h2, const float* __restrict__ b2,
                          float* __restrict__ out) {
    int j = threadIdx.x;
    int n = blockIdx.x * 4 + (j >> 5);
    int l = j & 31;
    if (n >= N_NODES) return;
    int beg = offs[n], end = offs[n + 1];
    float ad = ad2[n];

    float mx = -INFINITY;
    for (int p = beg + l; p < end; p += 32)
        mx = fmaxf(mx, lrelu(as2[csr[p]] + ad));
    for (int m = 16; m >= 1; m >>= 1) mx = fmaxf(mx, __shfl_xor(mx, m, 64));

    float dn = 0.f;
    for (int p = beg + l; p < end; p += 32)
        dn += expf(lrelu(as2[csr[p]] + ad) - mx);
    for (int m = 16; m >= 1; m >>= 1) dn += __shfl_xor(dn, m, 64);
    float rdn = 1.f / dn;

    float acc = 0.f;
    for (int p = beg; p < end; ++p) {
        int s = csr[p];
        float alpha = expf(lrelu(as2[s] + ad) - mx) * rdn;   // as2[s] broadcast
        acc += alpha * h2[s * 32 + l];                        // coalesced 128B gather
    }
    out[n * 32 + l] = acc + b2[l];
}

extern "C" void kernel_launch(void* const* d_in, const int* in_sizes, int n_in,
                              void* d_out, int out_size, void* d_ws, size_t ws_size,
                              hipStream_t stream) {
    const float* x        = (const float*)d_in[0];
    const int*   ei       = (const int*)d_in[1];
    const float* W1       = (const float*)d_in[2];
    const float* att_src1 = (const float*)d_in[3];
    const float* att_dst1 = (const float*)d_in[4];
    const float* b1       = (const float*)d_in[5];
    const float* W2       = (const float*)d_in[6];
    const float* att_src2 = (const float*)d_in[7];
    const float* att_dst2 = (const float*)d_in[8];
    const float* b2       = (const float*)d_in[9];
    float* out = (float*)d_out;

    // workspace carve-up
    float* p = (float*)d_ws;
    float* h1    = p; p += N_NODES * 128;   // 25.6 MB
    float* hact  = p; p += N_NODES * 128;   // 25.6 MB
    float* h2    = p; p += N_NODES * 32;    // 6.4 MB
    float* as1   = p; p += N_NODES * 4;
    float* ad1   = p; p += N_NODES * 4;
    float* as2   = p; p += N_NODES;
    float* ad2   = p; p += N_NODES;
    int* ip = (int*)p;
    int* cnt   = ip; ip += N_NODES;
    int* fill  = ip; ip += N_NODES;
    int* offs  = ip; ip += N_NODES + 1;
    int* bsums = ip; ip += 256;
    int* csr   = ip; ip += E_TOT;           // 3.4 MB

    const int nscan = (N_NODES + SCAN_BLK - 1) / SCAN_BLK;   // 98
    const int egrid = (E_TOT + 255) / 256;

    // ---- CSR build (graph shared by both layers) ----
    hipMemsetAsync(cnt,  0, N_NODES * sizeof(int), stream);
    hipMemsetAsync(fill, 0, N_NODES * sizeof(int), stream);
    count_edges<<<egrid, 256, 0, stream>>>(ei, cnt);
    scan_block<<<nscan, SCAN_BLK, 0, stream>>>(cnt, offs, bsums);
    scan_bsums<<<1, 64, 0, stream>>>(bsums, nscan);
    scan_add<<<nscan, SCAN_BLK, 0, stream>>>(offs, bsums);
    scatter_edges<<<egrid, 256, 0, stream>>>(ei, offs, fill, csr);

    // ---- layer 1 ----
    gemm1<<<N_NODES, 128, 0, stream>>>(x, W1, att_src1, att_dst1, h1, as1, ad1);
    node_agg1<<<N_NODES, 128, 0, stream>>>(offs, csr, as1, ad1, h1, b1, hact);

    // ---- layer 2 ----
    gemm2<<<N_NODES / 4, 128, 0, stream>>>(hact, W2, att_src2, att_dst2, h2, as2, ad2);
    node_agg2<<<(N_NODES + 3) / 4, 128, 0, stream>>>(offs, csr, as2, ad2, h2, b2, out);
}

// Round 3
// 316.056 us; speedup vs baseline: 3.0567x; 1.2273x over previous
//
#include <hip/hip_runtime.h>
#include <hip/hip_bf16.h>
#include <math.h>

#define N_NODES 50000
#define N_EDGES 800000
#define E_TOT   (N_EDGES + N_NODES)   // edges + self-loops
#define NEG_SLOPE 0.2f
#define SCAN_BLK 512
#define CAP1 512
#define CAP2 512

__device__ __forceinline__ float lrelu(float x) { return x >= 0.f ? x : NEG_SLOPE * x; }

__device__ __forceinline__ void edge_sd(const int* __restrict__ ei, int e, int& s, int& d) {
    if (e < N_EDGES) { s = ei[e]; d = ei[N_EDGES + e]; }
    else             { s = d = e - N_EDGES; }
}

// ======================= CSR build (by dst) =======================
__global__ void count_edges(const int* __restrict__ ei, int* __restrict__ cnt) {
    int e = blockIdx.x * blockDim.x + threadIdx.x;
    if (e >= E_TOT) return;
    int d = (e < N_EDGES) ? ei[N_EDGES + e] : e - N_EDGES;
    atomicAdd(&cnt[d], 1);
}

__global__ void scan_block(const int* __restrict__ cnt, int* __restrict__ offs,
                           int* __restrict__ bsums) {
    __shared__ int s[SCAN_BLK];
    int b = blockIdx.x, t = threadIdx.x;
    int i = b * SCAN_BLK + t;
    int v = (i < N_NODES) ? cnt[i] : 0;
    s[t] = v;
    __syncthreads();
    for (int off = 1; off < SCAN_BLK; off <<= 1) {
        int x = (t >= off) ? s[t - off] : 0;
        __syncthreads();
        s[t] += x;
        __syncthreads();
    }
    if (i < N_NODES) offs[i] = s[t] - v;   // exclusive
    if (t == SCAN_BLK - 1) bsums[b] = s[t];
}

__global__ void scan_bsums(int* __restrict__ bsums, int nb) {
    if (threadIdx.x == 0 && blockIdx.x == 0) {
        int acc = 0;
        for (int i = 0; i < nb; ++i) { int v = bsums[i]; bsums[i] = acc; acc += v; }
    }
}

__global__ void scan_add(int* __restrict__ offs, const int* __restrict__ bsums) {
    int b = blockIdx.x, t = threadIdx.x;
    int i = b * SCAN_BLK + t;
    if (i < N_NODES) offs[i] += bsums[b];
    if (b == 0 && t == 0) offs[N_NODES] = E_TOT;
}

__global__ void scatter_edges(const int* __restrict__ ei, const int* __restrict__ offs,
                              int* __restrict__ fill, int* __restrict__ csr) {
    int e = blockIdx.x * blockDim.x + threadIdx.x;
    if (e >= E_TOT) return;
    int s, d; edge_sd(ei, e, s, d);
    int pos = offs[d] + atomicAdd(&fill[d], 1);
    csr[pos] = s;
}

// ======================= layer 1 GEMM =======================
__global__ void gemm1(const float* __restrict__ x, const float* __restrict__ W1,
                      const float* __restrict__ att_s, const float* __restrict__ att_d,
                      float* __restrict__ h1, float* __restrict__ as1, float* __restrict__ ad1) {
    int n = blockIdx.x;
    int j = threadIdx.x;            // 0..127
    __shared__ float xs[64];
    if (j < 64) xs[j] = x[n * 64 + j];
    __syncthreads();
    float acc = 0.f;
#pragma unroll
    for (int k = 0; k < 64; ++k) acc += xs[k] * W1[k * 128 + j];
    h1[n * 128 + j] = acc;
    int h = j >> 5, l = j & 31;
    float ps = acc * att_s[h * 32 + l];
    float pd = acc * att_d[h * 32 + l];
    for (int m = 16; m >= 1; m >>= 1) {
        ps += __shfl_xor(ps, m, 64);
        pd += __shfl_xor(pd, m, 64);
    }
    if (l == 0) { as1[n * 4 + h] = ps; ad1[n * 4 + h] = pd; }
}

// ======================= layer 1 fused node aggregation =======================
// one block (128 threads) per dst node. Per-edge e/exp/alpha computed ONCE
// into LDS; phase C is pure fma over LDS-broadcast alpha x gathered h1.
__global__ void node_agg1(const int* __restrict__ offs, const int* __restrict__ csr,
                          const float* __restrict__ as1, const float* __restrict__ ad1,
                          const float* __restrict__ h1, const float* __restrict__ b1,
                          float* __restrict__ hact) {
    int n = blockIdx.x;
    int j = threadIdx.x;            // 0..127
    int h = j >> 5;
    int beg = offs[n], end = offs[n + 1], deg = end - beg;

    float4 ad = *(const float4*)(ad1 + n * 4);

    __shared__ float4 els[CAP1];    // 8 KB: per-edge e -> exp -> alpha
    __shared__ int   slds[CAP1];    // 2 KB: per-edge src
    __shared__ float4 red[128];     // 2 KB

    if (deg <= CAP1) {
        // ---- phase A: per-edge e into LDS + running max ----
        float4 mx = make_float4(-INFINITY, -INFINITY, -INFINITY, -INFINITY);
        for (int p = beg + j; p < end; p += 128) {
            int s = csr[p];
            float4 a = *(const float4*)(as1 + s * 4);
            float4 e = make_float4(lrelu(a.x + ad.x), lrelu(a.y + ad.y),
                                   lrelu(a.z + ad.z), lrelu(a.w + ad.w));
            els[p - beg] = e;
            slds[p - beg] = s;
            mx.x = fmaxf(mx.x, e.x); mx.y = fmaxf(mx.y, e.y);
            mx.z = fmaxf(mx.z, e.z); mx.w = fmaxf(mx.w, e.w);
        }
        red[j] = mx;
        __syncthreads();
        for (int st = 64; st >= 1; st >>= 1) {
            if (j < st) {
                float4 o = red[j + st], m = red[j];
                red[j] = make_float4(fmaxf(m.x, o.x), fmaxf(m.y, o.y),
                                     fmaxf(m.z, o.z), fmaxf(m.w, o.w));
            }
            __syncthreads();
        }
        float4 MX = red[0];
        __syncthreads();

        // ---- phase B: exp in place + denom ----
        float4 dn = make_float4(0.f, 0.f, 0.f, 0.f);
        for (int idx = j; idx < deg; idx += 128) {
            float4 e = els[idx];
            float4 ex = make_float4(expf(e.x - MX.x), expf(e.y - MX.y),
                                    expf(e.z - MX.z), expf(e.w - MX.w));
            els[idx] = ex;
            dn.x += ex.x; dn.y += ex.y; dn.z += ex.z; dn.w += ex.w;
        }
        red[j] = dn;
        __syncthreads();
        for (int st = 64; st >= 1; st >>= 1) {
            if (j < st) {
                float4 o = red[j + st], m = red[j];
                red[j] = make_float4(m.x + o.x, m.y + o.y, m.z + o.z, m.w + o.w);
            }
            __syncthreads();
        }
        float4 DN = red[0];
        float4 rr = make_float4(1.f / DN.x, 1.f / DN.y, 1.f / DN.z, 1.f / DN.w);
        __syncthreads();

        // ---- phase B2: prescale alpha = exp/denom ----
        for (int idx = j; idx < deg; idx += 128) {
            float4 v = els[idx];
            v.x *= rr.x; v.y *= rr.y; v.z *= rr.z; v.w *= rr.w;
            els[idx] = v;
        }
        __syncthreads();

        // ---- phase C: weighted aggregation ----
        float acc = 0.f;
        const float* ealpha = (const float*)els;
#pragma unroll 4
        for (int p = 0; p < deg; ++p) {
            float al = ealpha[p * 4 + h];                 // LDS broadcast per head group
            acc += al * h1[(size_t)slds[p] * 128 + j];    // coalesced 512B gather
        }
        float v = acc + b1[j];
        hact[n * 128 + j] = v > 0.f ? v : expm1f(v);
    } else {
        // ---- fallback (deg > CAP1): recompute path, rare/never ----
        float ad0 = ad.x, ad1v = ad.y, ad2v = ad.z, ad3v = ad.w;
        float4 mx = make_float4(-INFINITY, -INFINITY, -INFINITY, -INFINITY);
        for (int p = beg + j; p < end; p += 128) {
            int s = csr[p];
            float4 a = *(const float4*)(as1 + s * 4);
            mx.x = fmaxf(mx.x, lrelu(a.x + ad0)); mx.y = fmaxf(mx.y, lrelu(a.y + ad1v));
            mx.z = fmaxf(mx.z, lrelu(a.z + ad2v)); mx.w = fmaxf(mx.w, lrelu(a.w + ad3v));
        }
        red[j] = mx; __syncthreads();
        for (int st = 64; st >= 1; st >>= 1) {
            if (j < st) {
                float4 o = red[j + st], m = red[j];
                red[j] = make_float4(fmaxf(m.x, o.x), fmaxf(m.y, o.y),
                                     fmaxf(m.z, o.z), fmaxf(m.w, o.w));
            }
            __syncthreads();
        }
        float4 MX = red[0]; __syncthreads();
        float4 dn = make_float4(0.f, 0.f, 0.f, 0.f);
        for (int p = beg + j; p < end; p += 128) {
            int s = csr[p];
            float4 a = *(const float4*)(as1 + s * 4);
            dn.x += expf(lrelu(a.x + ad0) - MX.x); dn.y += expf(lrelu(a.y + ad1v) - MX.y);
            dn.z += expf(lrelu(a.z + ad2v) - MX.z); dn.w += expf(lrelu(a.w + ad3v) - MX.w);
        }
        red[j] = dn; __syncthreads();
        for (int st = 64; st >= 1; st >>= 1) {
            if (j < st) {
                float4 o = red[j + st], m = red[j];
                red[j] = make_float4(m.x + o.x, m.y + o.y, m.z + o.z, m.w + o.w);
            }
            __syncthreads();
        }
        float4 DN = red[0];
        float adh = (h == 0) ? ad0 : (h == 1) ? ad1v : (h == 2) ? ad2v : ad3v;
        float mxh = (h == 0) ? MX.x : (h == 1) ? MX.y : (h == 2) ? MX.z : MX.w;
        float rdh = 1.f / ((h == 0) ? DN.x : (h == 1) ? DN.y : (h == 2) ? DN.z : DN.w);
        float acc = 0.f;
        for (int p = beg; p < end; ++p) {
            int s = csr[p];
            float alpha = expf(lrelu(as1[s * 4 + h] + adh) - mxh) * rdh;
            acc += alpha * h1[(size_t)s * 128 + j];
        }
        float v = acc + b1[j];
        hact[n * 128 + j] = v > 0.f ? v : expm1f(v);
    }
}

// ======================= layer 2 GEMM =======================
__global__ void gemm2(const float* __restrict__ hsrc, const float* __restrict__ W2,
                      const float* __restrict__ att_s2, const float* __restrict__ att_d2,
                      float* __restrict__ h2, float* __restrict__ as2, float* __restrict__ ad2) {
    int nb = blockIdx.x * 4;
    int j = threadIdx.x;            // 0..127
    int nl = j >> 5, l = j & 31;
    __shared__ float hs[4][128];
    for (int i = j; i < 512; i += 128) hs[i >> 7][i & 127] = hsrc[nb * 128 + i];
    __syncthreads();
    int n = nb + nl;
    float acc = 0.f;
#pragma unroll
    for (int k = 0; k < 128; ++k) acc += hs[nl][k] * W2[k * 32 + l];
    h2[n * 32 + l] = acc;
    float ps = acc * att_s2[l];
    float pd = acc * att_d2[l];
    for (int m = 16; m >= 1; m >>= 1) {
        ps += __shfl_xor(ps, m, 64);
        pd += __shfl_xor(pd, m, 64);
    }
    if (l == 0) { as2[n] = ps; ad2[n] = pd; }
}

// ======================= layer 2 fused node aggregation =======================
// one wave (64 threads) per node; alpha computed once per edge into LDS;
// phase C splits edges across the two 32-lane halves.
__global__ void node_agg2(const int* __restrict__ offs, const int* __restrict__ csr,
                          const float* __restrict__ as2, const float* __restrict__ ad2,
                          const float* __restrict__ h2, const float* __restrict__ b2,
                          float* __restrict__ out) {
    int n = blockIdx.x;
    int t = threadIdx.x;            // 0..63
    int l = t & 31, half = t >> 5;
    int beg = offs[n], end = offs[n + 1], deg = end - beg;
    float ad = ad2[n];

    __shared__ float els[CAP2];
    __shared__ int  slds[CAP2];

    if (deg <= CAP2) {
        float mx = -INFINITY;
        for (int p = beg + t; p < end; p += 64) {
            int s = csr[p];
            float e = lrelu(as2[s] + ad);
            els[p - beg] = e;
            slds[p - beg] = s;
            mx = fmaxf(mx, e);
        }
        for (int m = 32; m >= 1; m >>= 1) mx = fmaxf(mx, __shfl_xor(mx, m, 64));
        __syncthreads();
        float dn = 0.f;
        for (int idx = t; idx < deg; idx += 64) {
            float ex = expf(els[idx] - mx);
            els[idx] = ex;
            dn += ex;
        }
        for (int m = 32; m >= 1; m >>= 1) dn += __shfl_xor(dn, m, 64);
        float r = 1.f / dn;
        __syncthreads();
        for (int idx = t; idx < deg; idx += 64) els[idx] *= r;
        __syncthreads();
        float acc = 0.f;
#pragma unroll 4
        for (int p = half; p < deg; p += 2)
            acc += els[p] * h2[(size_t)slds[p] * 32 + l];
        acc += __shfl_xor(acc, 32, 64);
        if (t < 32) out[n * 32 + l] = acc + b2[l];
    } else {
        // fallback recompute path
        float mx = -INFINITY;
        for (int p = beg + t; p < end; p += 64)
            mx = fmaxf(mx, lrelu(as2[csr[p]] + ad));
        for (int m = 32; m >= 1; m >>= 1) mx = fmaxf(mx, __shfl_xor(mx, m, 64));
        float dn = 0.f;
        for (int p = beg + t; p < end; p += 64)
            dn += expf(lrelu(as2[csr[p]] + ad) - mx);
        for (int m = 32; m >= 1; m >>= 1) dn += __shfl_xor(dn, m, 64);
        float r = 1.f / dn;
        float acc = 0.f;
        for (int p = beg + half; p < end; p += 2) {
            int s = csr[p];
            acc += expf(lrelu(as2[s] + ad) - mx) * r * h2[(size_t)s * 32 + l];
        }
        acc += __shfl_xor(acc, 32, 64);
        if (t < 32) out[n * 32 + l] = acc + b2[l];
    }
}

extern "C" void kernel_launch(void* const* d_in, const int* in_sizes, int n_in,
                              void* d_out, int out_size, void* d_ws, size_t ws_size,
                              hipStream_t stream) {
    const float* x        = (const float*)d_in[0];
    const int*   ei       = (const int*)d_in[1];
    const float* W1       = (const float*)d_in[2];
    const float* att_src1 = (const float*)d_in[3];
    const float* att_dst1 = (const float*)d_in[4];
    const float* b1       = (const float*)d_in[5];
    const float* W2       = (const float*)d_in[6];
    const float* att_src2 = (const float*)d_in[7];
    const float* att_dst2 = (const float*)d_in[8];
    const float* b2       = (const float*)d_in[9];
    float* out = (float*)d_out;

    // workspace carve-up
    float* p = (float*)d_ws;
    float* h1    = p; p += N_NODES * 128;   // 25.6 MB
    float* hact  = p; p += N_NODES * 128;   // 25.6 MB
    float* h2    = p; p += N_NODES * 32;    // 6.4 MB
    float* as1   = p; p += N_NODES * 4;
    float* ad1   = p; p += N_NODES * 4;
    float* as2   = p; p += N_NODES;
    float* ad2   = p; p += N_NODES;
    int* ip = (int*)p;
    int* cnt   = ip; ip += N_NODES;
    int* fill  = ip; ip += N_NODES;
    int* offs  = ip; ip += N_NODES + 1;
    int* bsums = ip; ip += 256;
    int* csr   = ip; ip += E_TOT;           // 3.4 MB

    const int nscan = (N_NODES + SCAN_BLK - 1) / SCAN_BLK;   // 98
    const int egrid = (E_TOT + 255) / 256;

    // ---- CSR build (graph shared by both layers) ----
    hipMemsetAsync(cnt,  0, N_NODES * sizeof(int), stream);
    hipMemsetAsync(fill, 0, N_NODES * sizeof(int), stream);
    count_edges<<<egrid, 256, 0, stream>>>(ei, cnt);
    scan_block<<<nscan, SCAN_BLK, 0, stream>>>(cnt, offs, bsums);
    scan_bsums<<<1, 64, 0, stream>>>(bsums, nscan);
    scan_add<<<nscan, SCAN_BLK, 0, stream>>>(offs, bsums);
    scatter_edges<<<egrid, 256, 0, stream>>>(ei, offs, fill, csr);

    // ---- layer 1 ----
    gemm1<<<N_NODES, 128, 0, stream>>>(x, W1, att_src1, att_dst1, h1, as1, ad1);
    node_agg1<<<N_NODES, 128, 0, stream>>>(offs, csr, as1, ad1, h1, b1, hact);

    // ---- layer 2 ----
    gemm2<<<N_NODES / 4, 128, 0, stream>>>(hact, W2, att_src2, att_dst2, h2, as2, ad2);
    node_agg2<<<N_NODES, 64, 0, stream>>>(offs, csr, as2, ad2, h2, b2, out);
}

// Round 5
// 257.022 us; speedup vs baseline: 3.7588x; 1.2297x over previous
//
#include <hip/hip_runtime.h>
#include <hip/hip_bf16.h>
#include <math.h>

#define N_NODES 50000
#define N_EDGES 800000
#define E_TOT   (N_EDGES + N_NODES)   // edges + self-loops
#define NEG_SLOPE 0.2f
#define SCAN_BLK 512
#define CAP1 128
#define CAP2 128

__device__ __forceinline__ float lrelu(float x) { return x >= 0.f ? x : NEG_SLOPE * x; }

__device__ __forceinline__ void edge_sd(const int* __restrict__ ei, int e, int& s, int& d) {
    if (e < N_EDGES) { s = ei[e]; d = ei[N_EDGES + e]; }
    else             { s = d = e - N_EDGES; }
}

// ======================= CSR build (by dst) =======================
__global__ void count_edges(const int* __restrict__ ei, int* __restrict__ cnt) {
    int e = blockIdx.x * blockDim.x + threadIdx.x;
    if (e >= E_TOT) return;
    int d = (e < N_EDGES) ? ei[N_EDGES + e] : e - N_EDGES;
    atomicAdd(&cnt[d], 1);
}

__global__ void scan_block(const int* __restrict__ cnt, int* __restrict__ offs,
                           int* __restrict__ bsums) {
    __shared__ int s[SCAN_BLK];
    int b = blockIdx.x, t = threadIdx.x;
    int i = b * SCAN_BLK + t;
    int v = (i < N_NODES) ? cnt[i] : 0;
    s[t] = v;
    __syncthreads();
    for (int off = 1; off < SCAN_BLK; off <<= 1) {
        int x = (t >= off) ? s[t - off] : 0;
        __syncthreads();
        s[t] += x;
        __syncthreads();
    }
    if (i < N_NODES) offs[i] = s[t] - v;   // exclusive
    if (t == SCAN_BLK - 1) bsums[b] = s[t];
}

// parallel single-block scan of block sums (nb <= SCAN_BLK)
__global__ void scan_bsums(int* __restrict__ bsums, int nb) {
    __shared__ int s[SCAN_BLK];
    int t = threadIdx.x;
    int v = (t < nb) ? bsums[t] : 0;
    s[t] = v;
    __syncthreads();
    for (int off = 1; off < SCAN_BLK; off <<= 1) {
        int x = (t >= off) ? s[t - off] : 0;
        __syncthreads();
        s[t] += x;
        __syncthreads();
    }
    if (t < nb) bsums[t] = s[t] - v;       // exclusive
}

__global__ void scan_add(int* __restrict__ offs, const int* __restrict__ bsums) {
    int b = blockIdx.x, t = threadIdx.x;
    int i = b * SCAN_BLK + t;
    if (i < N_NODES) offs[i] += bsums[b];
    if (b == 0 && t == 0) offs[N_NODES] = E_TOT;
}

__global__ void scatter_edges(const int* __restrict__ ei, const int* __restrict__ offs,
                              int* __restrict__ fill, int* __restrict__ csr) {
    int e = blockIdx.x * blockDim.x + threadIdx.x;
    if (e >= E_TOT) return;
    int s, d; edge_sd(ei, e, s, d);
    int pos = offs[d] + atomicAdd(&fill[d], 1);
    csr[pos] = s;
}

// ======================= layer 1 GEMM =======================
__global__ void gemm1(const float* __restrict__ x, const float* __restrict__ W1,
                      const float* __restrict__ att_s, const float* __restrict__ att_d,
                      float* __restrict__ h1, float* __restrict__ as1, float* __restrict__ ad1) {
    int n = blockIdx.x;
    int j = threadIdx.x;            // 0..127
    __shared__ float xs[64];
    if (j < 64) xs[j] = x[n * 64 + j];
    __syncthreads();
    float acc = 0.f;
#pragma unroll
    for (int k = 0; k < 64; ++k) acc += xs[k] * W1[k * 128 + j];
    h1[n * 128 + j] = acc;
    int h = j >> 5, l = j & 31;
    float ps = acc * att_s[h * 32 + l];
    float pd = acc * att_d[h * 32 + l];
    for (int m = 16; m >= 1; m >>= 1) {
        ps += __shfl_xor(ps, m, 64);
        pd += __shfl_xor(pd, m, 64);
    }
    if (l == 0) { as1[n * 4 + h] = ps; ad1[n * 4 + h] = pd; }
}

// ======================= layer 1 node agg + fused layer-2 GEMM ==============
// One block (128 thr) per dst node. No max pass (exp(e) is fp32-safe, softmax
// shift-invariant). No block reduction: denom accumulated redundantly per
// thread from the same LDS broadcasts phase C already reads. Then the hact
// row (in LDS) is immediately pushed through W2 + att2 dots -> h2/as2/ad2.
__global__ void node_agg1(const int* __restrict__ offs, const int* __restrict__ csr,
                          const float* __restrict__ as1, const float* __restrict__ ad1,
                          const float* __restrict__ h1, const float* __restrict__ b1,
                          const float* __restrict__ W2, const float* __restrict__ att_s2,
                          const float* __restrict__ att_d2,
                          float* __restrict__ h2, float* __restrict__ as2,
                          float* __restrict__ ad2) {
    int n = blockIdx.x;
    int j = threadIdx.x;            // 0..127
    int h = j >> 5, l = j & 31;
    int beg = offs[n], end = offs[n + 1], deg = end - beg;
    float4 ad = *(const float4*)(ad1 + n * 4);

    __shared__ float4 els[CAP1];    // 2 KB: per-edge exp(e) (4 heads)
    __shared__ int   slds[CAP1];    // 0.5 KB
    __shared__ float hrow[128];     // 0.5 KB: activated hact row
    __shared__ float redf[128];     // 0.5 KB: gemm2 partial reduce

    float v;
    if (deg <= CAP1) {
        // phase A: one pass, exp(e) straight into LDS
        for (int p = beg + j; p < end; p += 128) {
            int s = csr[p];
            float4 a = *(const float4*)(as1 + s * 4);
            float4 ex = make_float4(expf(lrelu(a.x + ad.x)), expf(lrelu(a.y + ad.y)),
                                    expf(lrelu(a.z + ad.z)), expf(lrelu(a.w + ad.w)));
            els[p - beg] = ex;
            slds[p - beg] = s;
        }
        __syncthreads();
        // phase C: weighted aggregation + inline denominator
        const float* ef = (const float*)els;
        float acc = 0.f, accE = 0.f;
#pragma unroll 8
        for (int p = 0; p < deg; ++p) {
            float ex = ef[p * 4 + h];                     // LDS broadcast per head group
            accE += ex;
            acc += ex * h1[(size_t)slds[p] * 128 + j];    // coalesced 512B gather
        }
        v = acc / accE + b1[j];
    } else {
        // fallback (deg > CAP1): recompute path; probability ~0
        float adh = (h == 0) ? ad.x : (h == 1) ? ad.y : (h == 2) ? ad.z : ad.w;
        float acc = 0.f, accE = 0.f;
        for (int p = beg; p < end; ++p) {
            int s = csr[p];
            float ex = expf(lrelu(as1[s * 4 + h] + adh));
            accE += ex;
            acc += ex * h1[(size_t)s * 128 + j];
        }
        v = acc / accE + b1[j];
    }
    v = v > 0.f ? v : expm1f(v);     // ELU
    hrow[j] = v;
    __syncthreads();

    // fused layer-2 GEMM: h2[n][l] = sum_k hrow[k] * W2[k][l], k-group = h
    float pacc = 0.f;
    int k0 = h * 32;
#pragma unroll
    for (int k = 0; k < 32; ++k)
        pacc += hrow[k0 + k] * W2[(k0 + k) * 32 + l];
    redf[j] = pacc;
    __syncthreads();
    if (j < 64) redf[j] += redf[j + 64];
    __syncthreads();
    if (j < 32) {
        float hv = redf[j] + redf[j + 32];
        h2[n * 32 + j] = hv;
        float ps = hv * att_s2[j];
        float pd = hv * att_d2[j];
        for (int m = 16; m >= 1; m >>= 1) {
            ps += __shfl_xor(ps, m, 64);
            pd += __shfl_xor(pd, m, 64);
        }
        if (j == 0) { as2[n] = ps; ad2[n] = pd; }
    }
}

// ======================= layer 2 node aggregation =======================
// One wave per node; no max pass, inline denominator; bias fused.
__global__ void node_agg2(const int* __restrict__ offs, const int* __restrict__ csr,
                          const float* __restrict__ as2, const float* __restrict__ ad2,
                          const float* __restrict__ h2, const float* __restrict__ b2,
                          float* __restrict__ out) {
    int n = blockIdx.x;
    int t = threadIdx.x;            // 0..63
    int l = t & 31, half = t >> 5;
    int beg = offs[n], end = offs[n + 1], deg = end - beg;
    float ad = ad2[n];

    __shared__ float els[CAP2];
    __shared__ int  slds[CAP2];

    float acc = 0.f, accE = 0.f;
    if (deg <= CAP2) {
        for (int p = beg + t; p < end; p += 64) {
            int s = csr[p];
            els[p - beg] = expf(lrelu(as2[s] + ad));
            slds[p - beg] = s;
        }
        __syncthreads();
#pragma unroll 8
        for (int p = half; p < deg; p += 2) {
            float ex = els[p];
            accE += ex;
            acc += ex * h2[(size_t)slds[p] * 32 + l];     // coalesced 128B gather
        }
    } else {
        for (int p = beg + half; p < end; p += 2) {
            int s = csr[p];
            float ex = expf(lrelu(as2[s] + ad));
            accE += ex;
            acc += ex * h2[(size_t)s * 32 + l];
        }
    }
    acc  += __shfl_xor(acc, 32, 64);
    accE += __shfl_xor(accE, 32, 64);
    if (t < 32) out[n * 32 + l] = acc / accE + b2[l];
}

extern "C" void kernel_launch(void* const* d_in, const int* in_sizes, int n_in,
                              void* d_out, int out_size, void* d_ws, size_t ws_size,
                              hipStream_t stream) {
    const float* x        = (const float*)d_in[0];
    const int*   ei       = (const int*)d_in[1];
    const float* W1       = (const float*)d_in[2];
    const float* att_src1 = (const float*)d_in[3];
    const float* att_dst1 = (const float*)d_in[4];
    const float* b1       = (const float*)d_in[5];
    const float* W2       = (const float*)d_in[6];
    const float* att_src2 = (const float*)d_in[7];
    const float* att_dst2 = (const float*)d_in[8];
    const float* b2       = (const float*)d_in[9];
    float* out = (float*)d_out;

    // workspace carve-up
    float* p = (float*)d_ws;
    float* h1    = p; p += N_NODES * 128;   // 25.6 MB
    float* h2    = p; p += N_NODES * 32;    // 6.4 MB
    float* as1   = p; p += N_NODES * 4;
    float* ad1   = p; p += N_NODES * 4;
    float* as2   = p; p += N_NODES;
    float* ad2   = p; p += N_NODES;
    int* ip = (int*)p;
    int* cnt   = ip; ip += N_NODES;
    int* fill  = ip; ip += N_NODES;
    int* offs  = ip; ip += N_NODES + 1;
    int* bsums = ip; ip += SCAN_BLK;
    int* csr   = ip; ip += E_TOT;           // 3.4 MB

    const int nscan = (N_NODES + SCAN_BLK - 1) / SCAN_BLK;   // 98
    const int egrid = (E_TOT + 255) / 256;

    // ---- CSR build (graph shared by both layers) ----
    hipMemsetAsync(cnt,  0, N_NODES * sizeof(int), stream);
    hipMemsetAsync(fill, 0, N_NODES * sizeof(int), stream);
    count_edges<<<egrid, 256, 0, stream>>>(ei, cnt);
    scan_block<<<nscan, SCAN_BLK, 0, stream>>>(cnt, offs, bsums);
    scan_bsums<<<1, SCAN_BLK, 0, stream>>>(bsums, nscan);
    scan_add<<<nscan, SCAN_BLK, 0, stream>>>(offs, bsums);
    scatter_edges<<<egrid, 256, 0, stream>>>(ei, offs, fill, csr);

    // ---- layer 1 (+ fused layer-2 GEMM) ----
    gemm1<<<N_NODES, 128, 0, stream>>>(x, W1, att_src1, att_dst1, h1, as1, ad1);
    node_agg1<<<N_NODES, 128, 0, stream>>>(offs, csr, as1, ad1, h1, b1,
                                           W2, att_src2, att_dst2, h2, as2, ad2);

    // ---- layer 2 aggregation ----
    node_agg2<<<N_NODES, 64, 0, stream>>>(offs, csr, as2, ad2, h2, b2, out);
}

// Round 6
// 246.205 us; speedup vs baseline: 3.9239x; 1.0439x over previous
//
#include <hip/hip_runtime.h>
#include <hip/hip_bf16.h>
#include <math.h>

#define N_NODES 50000
#define N_EDGES 800000
#define E_TOT   (N_EDGES + N_NODES)   // edges + self-loops
#define NEG_SLOPE 0.2f
#define SCAN_BLK 512
#define CAP1 128
#define CAP2 128

__device__ __forceinline__ float lrelu(float x) { return x >= 0.f ? x : NEG_SLOPE * x; }

__device__ __forceinline__ void edge_sd(const int* __restrict__ ei, int e, int& s, int& d) {
    if (e < N_EDGES) { s = ei[e]; d = ei[N_EDGES + e]; }
    else             { s = d = e - N_EDGES; }
}

// ======================= CSR build (by dst) =======================
__global__ void count_edges(const int* __restrict__ ei, int* __restrict__ cnt) {
    int e = blockIdx.x * blockDim.x + threadIdx.x;
    if (e >= E_TOT) return;
    int d = (e < N_EDGES) ? ei[N_EDGES + e] : e - N_EDGES;
    atomicAdd(&cnt[d], 1);
}

__global__ void scan_block(const int* __restrict__ cnt, int* __restrict__ offs,
                           int* __restrict__ bsums) {
    __shared__ int s[SCAN_BLK];
    int b = blockIdx.x, t = threadIdx.x;
    int i = b * SCAN_BLK + t;
    int v = (i < N_NODES) ? cnt[i] : 0;
    s[t] = v;
    __syncthreads();
    for (int off = 1; off < SCAN_BLK; off <<= 1) {
        int x = (t >= off) ? s[t - off] : 0;
        __syncthreads();
        s[t] += x;
        __syncthreads();
    }
    if (i < N_NODES) offs[i] = s[t] - v;   // exclusive
    if (t == SCAN_BLK - 1) bsums[b] = s[t];
}

// parallel single-block scan of block sums (nb <= SCAN_BLK)
__global__ void scan_bsums(int* __restrict__ bsums, int nb) {
    __shared__ int s[SCAN_BLK];
    int t = threadIdx.x;
    int v = (t < nb) ? bsums[t] : 0;
    s[t] = v;
    __syncthreads();
    for (int off = 1; off < SCAN_BLK; off <<= 1) {
        int x = (t >= off) ? s[t - off] : 0;
        __syncthreads();
        s[t] += x;
        __syncthreads();
    }
    if (t < nb) bsums[t] = s[t] - v;       // exclusive
}

__global__ void scan_add(int* __restrict__ offs, const int* __restrict__ bsums) {
    int b = blockIdx.x, t = threadIdx.x;
    int i = b * SCAN_BLK + t;
    if (i < N_NODES) offs[i] += bsums[b];
    if (b == 0 && t == 0) offs[N_NODES] = E_TOT;
}

__global__ void scatter_edges(const int* __restrict__ ei, const int* __restrict__ offs,
                              int* __restrict__ fill, int* __restrict__ csr) {
    int e = blockIdx.x * blockDim.x + threadIdx.x;
    if (e >= E_TOT) return;
    int s, d; edge_sd(ei, e, s, d);
    int pos = offs[d] + atomicAdd(&fill[d], 1);
    csr[pos] = s;
}

// ======================= layer 1 GEMM =======================
__global__ void gemm1(const float* __restrict__ x, const float* __restrict__ W1,
                      const float* __restrict__ att_s, const float* __restrict__ att_d,
                      float* __restrict__ h1, float* __restrict__ as1, float* __restrict__ ad1) {
    int n = blockIdx.x;
    int j = threadIdx.x;            // 0..127
    __shared__ float xs[64];
    if (j < 64) xs[j] = x[n * 64 + j];
    __syncthreads();
    float acc = 0.f;
#pragma unroll
    for (int k = 0; k < 64; ++k) acc += xs[k] * W1[k * 128 + j];
    h1[n * 128 + j] = acc;
    int h = j >> 5, l = j & 31;
    float ps = acc * att_s[h * 32 + l];
    float pd = acc * att_d[h * 32 + l];
    for (int m = 16; m >= 1; m >>= 1) {
        ps += __shfl_xor(ps, m, 64);
        pd += __shfl_xor(pd, m, 64);
    }
    if (l == 0) { as1[n * 4 + h] = ps; ad1[n * 4 + h] = pd; }
}

// ======================= layer 1 node agg + fused layer-2 GEMM ==============
// One block (128 thr) per dst node. Phase C: 4 edge-groups x 32 dim-quads,
// float4 gathers (wave covers 1KB/inst), LDS cross-group reduce. Then the
// activated row is pushed through W2 + att2 dots -> h2/as2/ad2.
__global__ void node_agg1(const int* __restrict__ offs, const int* __restrict__ csr,
                          const float* __restrict__ as1, const float* __restrict__ ad1,
                          const float* __restrict__ h1, const float* __restrict__ b1,
                          const float* __restrict__ W2, const float* __restrict__ att_s2,
                          const float* __restrict__ att_d2,
                          float* __restrict__ h2, float* __restrict__ as2,
                          float* __restrict__ ad2) {
    int n = blockIdx.x;
    int j = threadIdx.x;            // 0..127
    int h = j >> 5, l = j & 31;     // dim-role (phases A, gemm2)
    int q = j & 31, g = j >> 5;     // phase-C role: quad q (dims 4q..4q+3), edge-group g
    int beg = offs[n], end = offs[n + 1], deg = end - beg;
    float4 ad = *(const float4*)(ad1 + n * 4);

    __shared__ float4 els[CAP1];    // 2 KB: per-edge exp(e) (4 heads)
    __shared__ int   slds[CAP1];    // 0.5 KB
    __shared__ float4 raccs[4][32]; // 2 KB: cross-group partial sums
    __shared__ float raccE[4][32];  // 0.5 KB
    __shared__ float hrow[128];     // 0.5 KB: activated hact row
    __shared__ float redf[128];     // 0.5 KB: gemm2 partial reduce

    float v;
    if (deg <= CAP1) {
        // phase A: one pass, exp(e) straight into LDS
        for (int p = beg + j; p < end; p += 128) {
            int s = csr[p];
            float4 a = *(const float4*)(as1 + s * 4);
            float4 ex = make_float4(expf(lrelu(a.x + ad.x)), expf(lrelu(a.y + ad.y)),
                                    expf(lrelu(a.z + ad.z)), expf(lrelu(a.w + ad.w)));
            els[p - beg] = ex;
            slds[p - beg] = s;
        }
        __syncthreads();
        // phase C: float4 gathers, edges split across 4 groups
        const float* ef = (const float*)els;
        const float4* h1v = (const float4*)h1;
        int hq = q >> 3;                         // head of this quad
        float4 acc = make_float4(0.f, 0.f, 0.f, 0.f);
        float accE = 0.f;
#pragma unroll 4
        for (int p = g; p < deg; p += 4) {
            float ex = ef[p * 4 + hq];           // LDS broadcast
            accE += ex;
            float4 hv = h1v[(size_t)slds[p] * 32 + q];   // 16B/lane gather
            acc.x += ex * hv.x; acc.y += ex * hv.y;
            acc.z += ex * hv.z; acc.w += ex * hv.w;
        }
        raccs[g][q] = acc;
        raccE[g][q] = accE;
        __syncthreads();
        // thread j takes dim j: sum the 4 group partials
        int qq = j >> 2, rr = j & 3;
        float a0 = ((const float*)&raccs[0][qq])[rr] + ((const float*)&raccs[1][qq])[rr]
                 + ((const float*)&raccs[2][qq])[rr] + ((const float*)&raccs[3][qq])[rr];
        float aE = raccE[0][h << 3] + raccE[1][h << 3]
                 + raccE[2][h << 3] + raccE[3][h << 3];
        v = a0 / aE + b1[j];
    } else {
        // fallback (deg > CAP1): recompute path; probability ~0
        float adh = (h == 0) ? ad.x : (h == 1) ? ad.y : (h == 2) ? ad.z : ad.w;
        float acc = 0.f, accE = 0.f;
        for (int p = beg; p < end; ++p) {
            int s = csr[p];
            float ex = expf(lrelu(as1[s * 4 + h] + adh));
            accE += ex;
            acc += ex * h1[(size_t)s * 128 + j];
        }
        v = acc / accE + b1[j];
    }
    v = v > 0.f ? v : expm1f(v);     // ELU
    hrow[j] = v;
    __syncthreads();

    // fused layer-2 GEMM: h2[n][l] = sum_k hrow[k] * W2[k][l], k-group = h
    float pacc = 0.f;
    int k0 = h * 32;
#pragma unroll
    for (int k = 0; k < 32; ++k)
        pacc += hrow[k0 + k] * W2[(k0 + k) * 32 + l];
    redf[j] = pacc;
    __syncthreads();
    if (j < 64) redf[j] += redf[j + 64];
    __syncthreads();
    if (j < 32) {
        float hv = redf[j] + redf[j + 32];
        h2[n * 32 + j] = hv;
        float ps = hv * att_s2[j];
        float pd = hv * att_d2[j];
        for (int m = 16; m >= 1; m >>= 1) {
            ps += __shfl_xor(ps, m, 64);
            pd += __shfl_xor(pd, m, 64);
        }
        if (j == 0) { as2[n] = ps; ad2[n] = pd; }
    }
}

// ======================= layer 2 node aggregation =======================
// One wave per node; 8 edge-groups x 8 dim-quads, float4 gathers, butterfly
// shfl reduce; float4 output stores; bias fused.
__global__ void node_agg2(const int* __restrict__ offs, const int* __restrict__ csr,
                          const float* __restrict__ as2, const float* __restrict__ ad2,
                          const float* __restrict__ h2, const float* __restrict__ b2,
                          float* __restrict__ out) {
    int n = blockIdx.x;
    int t = threadIdx.x;            // 0..63
    int q = t & 7, g = t >> 3;      // quad q (dims 4q..4q+3), edge-group g
    int beg = offs[n], end = offs[n + 1], deg = end - beg;
    float ad = ad2[n];

    __shared__ float els[CAP2];
    __shared__ int  slds[CAP2];

    const float4* h2v = (const float4*)h2;
    float4 acc = make_float4(0.f, 0.f, 0.f, 0.f);
    float accE = 0.f;
    if (deg <= CAP2) {
        for (int p = beg + t; p < end; p += 64) {
            int s = csr[p];
            els[p - beg] = expf(lrelu(as2[s] + ad));
            slds[p - beg] = s;
        }
        __syncthreads();
#pragma unroll 4
        for (int p = g; p < deg; p += 8) {
            float ex = els[p];
            accE += ex;
            float4 hv = h2v[(size_t)slds[p] * 8 + q];
            acc.x += ex * hv.x; acc.y += ex * hv.y;
            acc.z += ex * hv.z; acc.w += ex * hv.w;
        }
    } else {
        for (int p = beg + g; p < end; p += 8) {
            int s = csr[p];
            float ex = expf(lrelu(as2[s] + ad));
            accE += ex;
            float4 hv = h2v[(size_t)s * 8 + q];
            acc.x += ex * hv.x; acc.y += ex * hv.y;
            acc.z += ex * hv.z; acc.w += ex * hv.w;
        }
    }
    // butterfly over the 8 edge-groups (same q across lanes t, t^8, t^16, t^32)
    for (int m = 8; m <= 32; m <<= 1) {
        acc.x += __shfl_xor(acc.x, m, 64);
        acc.y += __shfl_xor(acc.y, m, 64);
        acc.z += __shfl_xor(acc.z, m, 64);
        acc.w += __shfl_xor(acc.w, m, 64);
        accE  += __shfl_xor(accE,  m, 64);
    }
    if (t < 8) {
        float4 b = *(const float4*)(b2 + q * 4);
        float rE = 1.f / accE;
        float4 res = make_float4(acc.x * rE + b.x, acc.y * rE + b.y,
                                 acc.z * rE + b.z, acc.w * rE + b.w);
        *(float4*)(out + n * 32 + q * 4) = res;
    }
}

extern "C" void kernel_launch(void* const* d_in, const int* in_sizes, int n_in,
                              void* d_out, int out_size, void* d_ws, size_t ws_size,
                              hipStream_t stream) {
    const float* x        = (const float*)d_in[0];
    const int*   ei       = (const int*)d_in[1];
    const float* W1       = (const float*)d_in[2];
    const float* att_src1 = (const float*)d_in[3];
    const float* att_dst1 = (const float*)d_in[4];
    const float* b1       = (const float*)d_in[5];
    const float* W2       = (const float*)d_in[6];
    const float* att_src2 = (const float*)d_in[7];
    const float* att_dst2 = (const float*)d_in[8];
    const float* b2       = (const float*)d_in[9];
    float* out = (float*)d_out;

    // workspace carve-up
    float* p = (float*)d_ws;
    float* h1    = p; p += N_NODES * 128;   // 25.6 MB
    float* h2    = p; p += N_NODES * 32;    // 6.4 MB
    float* as1   = p; p += N_NODES * 4;
    float* ad1   = p; p += N_NODES * 4;
    float* as2   = p; p += N_NODES;
    float* ad2   = p; p += N_NODES;
    int* ip = (int*)p;
    int* cnt   = ip; ip += N_NODES;
    int* fill  = ip; ip += N_NODES;
    int* offs  = ip; ip += N_NODES + 1;
    int* bsums = ip; ip += SCAN_BLK;
    int* csr   = ip; ip += E_TOT;           // 3.4 MB

    const int nscan = (N_NODES + SCAN_BLK - 1) / SCAN_BLK;   // 98
    const int egrid = (E_TOT + 255) / 256;

    // ---- CSR build (graph shared by both layers) ----
    hipMemsetAsync(cnt,  0, N_NODES * sizeof(int), stream);
    hipMemsetAsync(fill, 0, N_NODES * sizeof(int), stream);
    count_edges<<<egrid, 256, 0, stream>>>(ei, cnt);
    scan_block<<<nscan, SCAN_BLK, 0, stream>>>(cnt, offs, bsums);
    scan_bsums<<<1, SCAN_BLK, 0, stream>>>(bsums, nscan);
    scan_add<<<nscan, SCAN_BLK, 0, stream>>>(offs, bsums);
    scatter_edges<<<egrid, 256, 0, stream>>>(ei, offs, fill, csr);

    // ---- layer 1 (+ fused layer-2 GEMM) ----
    gemm1<<<N_NODES, 128, 0, stream>>>(x, W1, att_src1, att_dst1, h1, as1, ad1);
    node_agg1<<<N_NODES, 128, 0, stream>>>(offs, csr, as1, ad1, h1, b1,
                                           W2, att_src2, att_dst2, h2, as2, ad2);

    // ---- layer 2 aggregation ----
    node_agg2<<<N_NODES, 64, 0, stream>>>(offs, csr, as2, ad2, h2, b2, out);
}

// Round 7
// 229.180 us; speedup vs baseline: 4.2154x; 1.0743x over previous
//
#include <hip/hip_runtime.h>
#include <hip/hip_bf16.h>
#include <math.h>

#define N_NODES 50000
#define N_EDGES 800000
#define E_TOT   (N_EDGES + N_NODES)   // edges + self-loops
#define NEG_SLOPE 0.2f
#define SCAN_BLK 512
#define CAP1 128
#define CAP2 128

__device__ __forceinline__ float lrelu(float x) { return x >= 0.f ? x : NEG_SLOPE * x; }

// round-to-nearest-even fp32 -> bf16 (as uint16 in low bits)
__device__ __forceinline__ unsigned bf16r(float x) {
    unsigned u = __float_as_uint(x);
    return (u + 0x7fffu + ((u >> 16) & 1u)) >> 16;
}
__device__ __forceinline__ unsigned pack2(float lo, float hi) {
    return bf16r(lo) | (bf16r(hi) << 16);
}
__device__ __forceinline__ float bflo(unsigned u) { return __uint_as_float(u << 16); }
__device__ __forceinline__ float bfhi(unsigned u) { return __uint_as_float(u & 0xffff0000u); }

__device__ __forceinline__ void edge_sd(const int* __restrict__ ei, int e, int& s, int& d) {
    if (e < N_EDGES) { s = ei[e]; d = ei[N_EDGES + e]; }
    else             { s = d = e - N_EDGES; }
}

// ======================= CSR build (by dst) =======================
__global__ void count_edges(const int* __restrict__ ei, int* __restrict__ cnt) {
    int e = blockIdx.x * blockDim.x + threadIdx.x;
    if (e >= E_TOT) return;
    int d = (e < N_EDGES) ? ei[N_EDGES + e] : e - N_EDGES;
    atomicAdd(&cnt[d], 1);
}

__global__ void scan_block(const int* __restrict__ cnt, int* __restrict__ offs,
                           int* __restrict__ bsums) {
    __shared__ int s[SCAN_BLK];
    int b = blockIdx.x, t = threadIdx.x;
    int i = b * SCAN_BLK + t;
    int v = (i < N_NODES) ? cnt[i] : 0;
    s[t] = v;
    __syncthreads();
    for (int off = 1; off < SCAN_BLK; off <<= 1) {
        int x = (t >= off) ? s[t - off] : 0;
        __syncthreads();
        s[t] += x;
        __syncthreads();
    }
    if (i < N_NODES) offs[i] = s[t] - v;   // exclusive
    if (t == SCAN_BLK - 1) bsums[b] = s[t];
}

__global__ void scan_bsums(int* __restrict__ bsums, int nb) {
    __shared__ int s[SCAN_BLK];
    int t = threadIdx.x;
    int v = (t < nb) ? bsums[t] : 0;
    s[t] = v;
    __syncthreads();
    for (int off = 1; off < SCAN_BLK; off <<= 1) {
        int x = (t >= off) ? s[t - off] : 0;
        __syncthreads();
        s[t] += x;
        __syncthreads();
    }
    if (t < nb) bsums[t] = s[t] - v;       // exclusive
}

__global__ void scan_add(int* __restrict__ offs, const int* __restrict__ bsums) {
    int b = blockIdx.x, t = threadIdx.x;
    int i = b * SCAN_BLK + t;
    if (i < N_NODES) offs[i] += bsums[b];
    if (b == 0 && t == 0) offs[N_NODES] = E_TOT;
}

__global__ void scatter_edges(const int* __restrict__ ei, const int* __restrict__ offs,
                              int* __restrict__ fill, int* __restrict__ csr) {
    int e = blockIdx.x * blockDim.x + threadIdx.x;
    if (e >= E_TOT) return;
    int s, d; edge_sd(ei, e, s, d);
    int pos = offs[d] + atomicAdd(&fill[d], 1);
    csr[pos] = s;
}

// ======================= layer 1 GEMM (h1 stored bf16-packed) ===============
__global__ void gemm1(const float* __restrict__ x, const float* __restrict__ W1,
                      const float* __restrict__ att_s, const float* __restrict__ att_d,
                      unsigned* __restrict__ h1u, float* __restrict__ as1,
                      float* __restrict__ ad1) {
    int n = blockIdx.x;
    int j = threadIdx.x;            // 0..127
    __shared__ float xs[64];
    __shared__ float hrow[128];
    if (j < 64) xs[j] = x[n * 64 + j];
    __syncthreads();
    float acc = 0.f;
#pragma unroll
    for (int k = 0; k < 64; ++k) acc += xs[k] * W1[k * 128 + j];
    hrow[j] = acc;
    int h = j >> 5, l = j & 31;
    float ps = acc * att_s[h * 32 + l];
    float pd = acc * att_d[h * 32 + l];
    for (int m = 16; m >= 1; m >>= 1) {
        ps += __shfl_xor(ps, m, 64);
        pd += __shfl_xor(pd, m, 64);
    }
    if (l == 0) { as1[n * 4 + h] = ps; ad1[n * 4 + h] = pd; }
    __syncthreads();
    if (j < 64) h1u[n * 64 + j] = pack2(hrow[2 * j], hrow[2 * j + 1]);
}

// ======================= layer 1 node agg + fused layer-2 GEMM ==============
// One block (128 thr) per dst node. Phase C: 8 edge-groups x 16 octs; each
// lane gathers 16B = 8 bf16 dims; LDS cross-group reduce. Activated row then
// pushed through W2 + att2 dots -> h2 (bf16) / as2 / ad2.
__global__ void node_agg1(const int* __restrict__ offs, const int* __restrict__ csr,
                          const float* __restrict__ as1, const float* __restrict__ ad1,
                          const uint4* __restrict__ h1q, const unsigned* __restrict__ h1u,
                          const float* __restrict__ b1,
                          const float* __restrict__ W2, const float* __restrict__ att_s2,
                          const float* __restrict__ att_d2,
                          unsigned* __restrict__ h2u, float* __restrict__ as2,
                          float* __restrict__ ad2) {
    int n = blockIdx.x;
    int j = threadIdx.x;            // 0..127
    int h = j >> 5, l = j & 31;
    int beg = offs[n], end = offs[n + 1], deg = end - beg;
    float4 ad = *(const float4*)(ad1 + n * 4);

    __shared__ float4 els[CAP1];    // 2 KB: per-edge exp(e) (4 heads)
    __shared__ int   slds[CAP1];    // 0.5 KB
    __shared__ float4 racc4[8][32]; // 4 KB: cross-group partials ([g][128 dims])
    __shared__ float raccE[8][16];  // 0.5 KB
    __shared__ float hrow[128];     // 0.5 KB
    __shared__ float redf[128];     // 0.5 KB

    float v;
    if (deg <= CAP1) {
        // phase A: exp(e) straight into LDS
        for (int p = beg + j; p < end; p += 128) {
            int s = csr[p];
            float4 a = *(const float4*)(as1 + s * 4);
            float4 ex = make_float4(expf(lrelu(a.x + ad.x)), expf(lrelu(a.y + ad.y)),
                                    expf(lrelu(a.z + ad.z)), expf(lrelu(a.w + ad.w)));
            els[p - beg] = ex;
            slds[p - beg] = s;
        }
        __syncthreads();
        // phase C: 8 edge-groups x 16 octs, 16B bf16 gathers
        int oct = j & 15, g = j >> 4;
        int hq = oct >> 2;                       // head of this oct
        const float* ef = (const float*)els;
        float a0 = 0.f, a1 = 0.f, a2 = 0.f, a3 = 0.f;
        float a4 = 0.f, a5 = 0.f, a6 = 0.f, a7 = 0.f;
        float accE = 0.f;
#pragma unroll 2
        for (int p = g; p < deg; p += 8) {
            float ex = ef[p * 4 + hq];           // LDS broadcast
            accE += ex;
            uint4 hv = h1q[(size_t)slds[p] * 16 + oct];   // 16B/lane gather
            a0 += ex * bflo(hv.x); a1 += ex * bfhi(hv.x);
            a2 += ex * bflo(hv.y); a3 += ex * bfhi(hv.y);
            a4 += ex * bflo(hv.z); a5 += ex * bfhi(hv.z);
            a6 += ex * bflo(hv.w); a7 += ex * bfhi(hv.w);
        }
        racc4[g][oct * 2]     = make_float4(a0, a1, a2, a3);
        racc4[g][oct * 2 + 1] = make_float4(a4, a5, a6, a7);
        raccE[g][oct] = accE;
        __syncthreads();
        // dim j: sum the 8 group partials
        const float* rf = (const float*)racc4;
        float sa = 0.f, sE = 0.f;
#pragma unroll
        for (int gg = 0; gg < 8; ++gg) {
            sa += rf[gg * 128 + j];
            sE += raccE[gg][h * 4];
        }
        v = sa / sE + b1[j];
    } else {
        // fallback (deg > CAP1): recompute path; probability ~0
        float adh = (h == 0) ? ad.x : (h == 1) ? ad.y : (h == 2) ? ad.z : ad.w;
        float acc = 0.f, accE = 0.f;
        for (int p = beg; p < end; ++p) {
            int s = csr[p];
            float ex = expf(lrelu(as1[s * 4 + h] + adh));
            accE += ex;
            unsigned u = h1u[(size_t)s * 64 + (j >> 1)];
            acc += ex * ((j & 1) ? bfhi(u) : bflo(u));
        }
        v = acc / accE + b1[j];
    }
    v = v > 0.f ? v : expm1f(v);     // ELU
    hrow[j] = v;
    __syncthreads();

    // fused layer-2 GEMM: h2[n][l] = sum_k hrow[k] * W2[k][l], k-group = h
    float pacc = 0.f;
    int k0 = h * 32;
#pragma unroll
    for (int k = 0; k < 32; ++k)
        pacc += hrow[k0 + k] * W2[(k0 + k) * 32 + l];
    redf[j] = pacc;
    __syncthreads();
    if (j < 64) redf[j] += redf[j + 64];
    __syncthreads();
    if (j < 32) {
        float hv = redf[j] + redf[j + 32];
        float ps = hv * att_s2[j];
        float pd = hv * att_d2[j];
        for (int m = 16; m >= 1; m >>= 1) {
            ps += __shfl_xor(ps, m, 64);
            pd += __shfl_xor(pd, m, 64);
        }
        if (j == 0) { as2[n] = ps; ad2[n] = pd; }
        float hv1 = __shfl_down(hv, 1, 64);
        if ((j & 1) == 0) h2u[n * 16 + (j >> 1)] = pack2(hv, hv1);
    }
}

// ======================= layer 2 node aggregation =======================
// One wave per node; 16 edge-groups x 4 octs (8 bf16 dims each), butterfly
// shfl reduce; fp32 float4 stores; bias fused.
__global__ void node_agg2(const int* __restrict__ offs, const int* __restrict__ csr,
                          const float* __restrict__ as2, const float* __restrict__ ad2,
                          const uint4* __restrict__ h2q, const float* __restrict__ b2,
                          float* __restrict__ out) {
    int n = blockIdx.x;
    int t = threadIdx.x;            // 0..63
    int oct = t & 3, g = t >> 2;    // oct: dims 8*oct.., 16 edge-groups
    int beg = offs[n], end = offs[n + 1], deg = end - beg;
    float ad = ad2[n];

    __shared__ float els[CAP2];
    __shared__ int  slds[CAP2];

    float a0 = 0.f, a1 = 0.f, a2 = 0.f, a3 = 0.f;
    float a4 = 0.f, a5 = 0.f, a6 = 0.f, a7 = 0.f;
    float accE = 0.f;
    if (deg <= CAP2) {
        for (int p = beg + t; p < end; p += 64) {
            int s = csr[p];
            els[p - beg] = expf(lrelu(as2[s] + ad));
            slds[p - beg] = s;
        }
        __syncthreads();
        for (int p = g; p < deg; p += 16) {
            float ex = els[p];
            accE += ex;
            uint4 hv = h2q[(size_t)slds[p] * 4 + oct];
            a0 += ex * bflo(hv.x); a1 += ex * bfhi(hv.x);
            a2 += ex * bflo(hv.y); a3 += ex * bfhi(hv.y);
            a4 += ex * bflo(hv.z); a5 += ex * bfhi(hv.z);
            a6 += ex * bflo(hv.w); a7 += ex * bfhi(hv.w);
        }
    } else {
        for (int p = beg + g; p < end; p += 16) {
            int s = csr[p];
            float ex = expf(lrelu(as2[s] + ad));
            accE += ex;
            uint4 hv = h2q[(size_t)s * 4 + oct];
            a0 += ex * bflo(hv.x); a1 += ex * bfhi(hv.x);
            a2 += ex * bflo(hv.y); a3 += ex * bfhi(hv.y);
            a4 += ex * bflo(hv.z); a5 += ex * bfhi(hv.z);
            a6 += ex * bflo(hv.w); a7 += ex * bfhi(hv.w);
        }
    }
    // butterfly over the 16 edge-groups (lanes sharing oct = t&3)
    for (int m = 4; m <= 32; m <<= 1) {
        a0 += __shfl_xor(a0, m, 64); a1 += __shfl_xor(a1, m, 64);
        a2 += __shfl_xor(a2, m, 64); a3 += __shfl_xor(a3, m, 64);
        a4 += __shfl_xor(a4, m, 64); a5 += __shfl_xor(a5, m, 64);
        a6 += __shfl_xor(a6, m, 64); a7 += __shfl_xor(a7, m, 64);
        accE += __shfl_xor(accE, m, 64);
    }
    if (t < 4) {
        float rE = 1.f / accE;
        const float4* bb = (const float4*)(b2 + t * 8);
        float4 r0 = make_float4(a0 * rE + bb[0].x, a1 * rE + bb[0].y,
                                a2 * rE + bb[0].z, a3 * rE + bb[0].w);
        float4 r1 = make_float4(a4 * rE + bb[1].x, a5 * rE + bb[1].y,
                                a6 * rE + bb[1].z, a7 * rE + bb[1].w);
        *(float4*)(out + n * 32 + t * 8)     = r0;
        *(float4*)(out + n * 32 + t * 8 + 4) = r1;
    }
}

extern "C" void kernel_launch(void* const* d_in, const int* in_sizes, int n_in,
                              void* d_out, int out_size, void* d_ws, size_t ws_size,
                              hipStream_t stream) {
    const float* x        = (const float*)d_in[0];
    const int*   ei       = (const int*)d_in[1];
    const float* W1       = (const float*)d_in[2];
    const float* att_src1 = (const float*)d_in[3];
    const float* att_dst1 = (const float*)d_in[4];
    const float* b1       = (const float*)d_in[5];
    const float* W2       = (const float*)d_in[6];
    const float* att_src2 = (const float*)d_in[7];
    const float* att_dst2 = (const float*)d_in[8];
    const float* b2       = (const float*)d_in[9];
    float* out = (float*)d_out;

    // workspace carve-up
    float* p = (float*)d_ws;
    unsigned* h1u = (unsigned*)p; p += N_NODES * 64;   // bf16 h1, 12.8 MB
    unsigned* h2u = (unsigned*)p; p += N_NODES * 16;   // bf16 h2, 3.2 MB
    float* as1   = p; p += N_NODES * 4;
    float* ad1   = p; p += N_NODES * 4;
    float* as2   = p; p += N_NODES;
    float* ad2   = p; p += N_NODES;
    int* ip = (int*)p;
    int* cnt   = ip; ip += N_NODES;
    int* fill  = ip; ip += N_NODES;
    int* offs  = ip; ip += N_NODES + 1;
    int* bsums = ip; ip += SCAN_BLK;
    int* csr   = ip; ip += E_TOT;           // 3.4 MB

    const int nscan = (N_NODES + SCAN_BLK - 1) / SCAN_BLK;   // 98
    const int egrid = (E_TOT + 255) / 256;

    // ---- CSR build (graph shared by both layers) ----
    hipMemsetAsync(cnt,  0, N_NODES * sizeof(int), stream);
    hipMemsetAsync(fill, 0, N_NODES * sizeof(int), stream);
    count_edges<<<egrid, 256, 0, stream>>>(ei, cnt);
    scan_block<<<nscan, SCAN_BLK, 0, stream>>>(cnt, offs, bsums);
    scan_bsums<<<1, SCAN_BLK, 0, stream>>>(bsums, nscan);
    scan_add<<<nscan, SCAN_BLK, 0, stream>>>(offs, bsums);
    scatter_edges<<<egrid, 256, 0, stream>>>(ei, offs, fill, csr);

    // ---- layer 1 (+ fused layer-2 GEMM) ----
    gemm1<<<N_NODES, 128, 0, stream>>>(x, W1, att_src1, att_dst1, h1u, as1, ad1);
    node_agg1<<<N_NODES, 128, 0, stream>>>(offs, csr, as1, ad1,
                                           (const uint4*)h1u, h1u, b1,
                                           W2, att_src2, att_dst2, h2u, as2, ad2);

    // ---- layer 2 aggregation ----
    node_agg2<<<N_NODES, 64, 0, stream>>>(offs, csr, as2, ad2,
                                          (const uint4*)h2u, b2, out);
}